// Round 6
// baseline (221.547 us; speedup 1.0000x reference)
//
#include <hip/hip_runtime.h>
#include <hip/hip_bf16.h>

#define B_  2
#define S_  2048
#define H_  1024
#define NH_ 16
#define HD_ 64
#define NTOK (B_*S_)   // 4096

typedef __attribute__((ext_vector_type(8))) short bf16x8;
typedef __attribute__((ext_vector_type(4))) float f32x4;

#define SC2 0.18033688011112042f   // (1/sqrt(64)) * log2(e)

static __device__ __forceinline__ ushort f2bf(float f) {
    __hip_bfloat16 h = __float2bfloat16(f);
    return *reinterpret_cast<ushort*>(&h);
}

static __device__ __forceinline__ void gload_lds16(const void* g, void* l) {
    __builtin_amdgcn_global_load_lds(
        (const __attribute__((address_space(1))) void*)g,
        (__attribute__((address_space(3))) void*)l,
        16, 0, 0);
}

// ---------------------------------------------------------------
// f32 -> bf16 bulk converts
// ---------------------------------------------------------------
__global__ __launch_bounds__(256) void f32_to_bf16(
    const float* __restrict__ s, ushort* __restrict__ d, int n8)
{
    const int i = blockIdx.x * 256 + threadIdx.x;
    if (i >= n8) return;
    const float4 a = reinterpret_cast<const float4*>(s)[2*i + 0];
    const float4 b = reinterpret_cast<const float4*>(s)[2*i + 1];
    ushort u[8];
    u[0] = f2bf(a.x); u[1] = f2bf(a.y); u[2] = f2bf(a.z); u[3] = f2bf(a.w);
    u[4] = f2bf(b.x); u[5] = f2bf(b.y); u[6] = f2bf(b.z); u[7] = f2bf(b.w);
    reinterpret_cast<uint4*>(d)[i] = *reinterpret_cast<uint4*>(u);
}

struct Cvt4 { const float* s[4]; ushort* d[4]; };
__global__ __launch_bounds__(256) void w_to_bf16(Cvt4 a, int n8)
{
    const int z = blockIdx.y;
    const int i = blockIdx.x * 256 + threadIdx.x;
    if (i >= n8) return;
    const float* s = a.s[z];
    const float4 va = reinterpret_cast<const float4*>(s)[2*i + 0];
    const float4 vb = reinterpret_cast<const float4*>(s)[2*i + 1];
    ushort u[8];
    u[0] = f2bf(va.x); u[1] = f2bf(va.y); u[2] = f2bf(va.z); u[3] = f2bf(va.w);
    u[4] = f2bf(vb.x); u[5] = f2bf(vb.y); u[6] = f2bf(vb.z); u[7] = f2bf(vb.w);
    reinterpret_cast<uint4*>(a.d[z])[i] = *reinterpret_cast<uint4*>(u);
}

// ---------------------------------------------------------------
// V [tok][H] bf16 -> Vt [(b*NH+h)][d][s] bf16
// ---------------------------------------------------------------
__global__ __launch_bounds__(256) void transpose_v(
    const ushort* __restrict__ Vb, ushort* __restrict__ Vt)
{
    __shared__ ushort T[64][72];
    const int t  = threadIdx.x;
    const int b  = blockIdx.z;
    const int h  = blockIdx.y;
    const int s0 = blockIdx.x * 64;
    const int r  = t >> 2;
    const int c0 = (t & 3) * 16;

    const ushort* src = Vb + (size_t)(b*S_ + s0 + r)*H_ + h*HD_ + c0;
    *reinterpret_cast<uint4*>(&T[r][c0])     = *reinterpret_cast<const uint4*>(src);
    *reinterpret_cast<uint4*>(&T[r][c0 + 8]) = *reinterpret_cast<const uint4*>(src + 8);
    __syncthreads();

    const int d = r;
    ushort tmp[16];
#pragma unroll
    for (int k = 0; k < 16; ++k) tmp[k] = T[c0 + k][d];
    ushort* dst = Vt + ((size_t)((b*NH_ + h)*HD_ + d))*S_ + s0 + c0;
    *reinterpret_cast<uint4*>(dst)     = *reinterpret_cast<uint4*>(&tmp[0]);
    *reinterpret_cast<uint4*>(dst + 8) = *reinterpret_cast<uint4*>(&tmp[8]);
}

// ---------------------------------------------------------------
// MFMA GEMM: Y = A(bf16,[M,K]) @ W(bf16,[N,K])^T + bias(f32)
// ---------------------------------------------------------------
struct GemmArgs {
    const ushort* W[3];
    const float*  bias[3];
    void*         Y[3];
};

template<int MREP, bool BF16OUT>
__global__ __launch_bounds__(256) void gemm_mfma_bt(
    const ushort* __restrict__ A, GemmArgs args, int M, int N, int K)
{
    constexpr int BM = MREP * 32;
    __shared__ __align__(16) ushort As[BM * 64];
    __shared__ __align__(16) ushort Bs[128 * 64];

    const int z = blockIdx.z;
    const ushort* __restrict__ W   = args.W[z];
    const float*  __restrict__ bia = args.bias[z];

    const int t  = threadIdx.x;
    const int w  = t >> 6;
    const int l  = t & 63;
    const int lq = l >> 4;
    const int ln = l & 15;
    const int wr = w >> 1;
    const int wc = w & 1;
    const int m0 = blockIdx.x * BM;
    const int n0 = blockIdx.y * 128;
    const int srow = l >> 3;
    const int scol = (l & 7) * 8;

    f32x4 acc[MREP][4];
#pragma unroll
    for (int m = 0; m < MREP; ++m)
#pragma unroll
        for (int n = 0; n < 4; ++n) acc[m][n] = f32x4{0.f, 0.f, 0.f, 0.f};

    for (int k0 = 0; k0 < K; k0 += 64) {
        __syncthreads();
#pragma unroll
        for (int i = 0; i < BM/32; ++i) {
            const int rb = i*32 + w*8;
            gload_lds16(A + (size_t)(m0 + rb + srow)*K + k0 + scol, &As[rb*64]);
        }
#pragma unroll
        for (int i = 0; i < 4; ++i) {
            const int rb = i*32 + w*8;
            gload_lds16(W + (size_t)(n0 + rb + srow)*K + k0 + scol, &Bs[rb*64]);
        }
        __syncthreads();
#pragma unroll
        for (int ks = 0; ks < 2; ++ks) {
            bf16x8 bfr[4];
#pragma unroll
            for (int n = 0; n < 4; ++n)
                bfr[n] = *reinterpret_cast<const bf16x8*>(&Bs[(wc*64 + n*16 + ln)*64 + ks*32 + lq*8]);
#pragma unroll
            for (int m = 0; m < MREP; ++m) {
                const bf16x8 afr = *reinterpret_cast<const bf16x8*>(&As[(wr*MREP*16 + m*16 + ln)*64 + ks*32 + lq*8]);
#pragma unroll
                for (int n = 0; n < 4; ++n)
                    acc[m][n] = __builtin_amdgcn_mfma_f32_16x16x32_bf16(afr, bfr[n], acc[m][n], 0, 0, 0);
            }
        }
    }

    float bv[4];
#pragma unroll
    for (int n = 0; n < 4; ++n) bv[n] = bia[n0 + wc*64 + n*16 + ln];

#pragma unroll
    for (int m = 0; m < MREP; ++m) {
#pragma unroll
        for (int r = 0; r < 4; ++r) {
            const size_t row = (size_t)(m0 + wr*MREP*16 + m*16 + lq*4 + r);
#pragma unroll
            for (int n = 0; n < 4; ++n) {
                const int col = n0 + wc*64 + n*16 + ln;
                const float val = acc[m][n][r] + bv[n];
                if constexpr (BF16OUT)
                    ((ushort*)args.Y[z])[row*N + col] = f2bf(val);
                else
                    ((float*)args.Y[z])[row*N + col] = val;
            }
        }
    }
}

// ---------------------------------------------------------------
// attn_pv (round 6): QB=128, swapped QK^T (mfma(K,Q) -> lane-local
// q rows, 4-consecutive-key P values -> packed b64 P stores),
// deferred normalization, exp2f.
// Wave w owns q rows [q0 + w*32, +32) as 2 sub-tiles of 16.
// ---------------------------------------------------------------
__global__ __launch_bounds__(256) void attn_pv(
    const ushort* __restrict__ Qb, const ushort* __restrict__ Kb,
    const ushort* __restrict__ Vtg, ushort* __restrict__ ctx,
    float* __restrict__ invl_g)
{
    __shared__ __align__(16) ushort Ks[64*64];      // swizzled K tile [key][d]
    __shared__ __align__(16) ushort Vs[64*64];      // swizzled V^T tile [d][key]
    __shared__ __align__(16) ushort Ps[4][32][72];  // per-wave P [qrow][key]

    const int t  = threadIdx.x;
    const int w  = t >> 6;
    const int l  = t & 63;
    const int lq = l >> 4;
    const int ln = l & 15;
    const int b  = blockIdx.z;
    const int h  = blockIdx.y;
    const int q0 = blockIdx.x * 128;

    // Q B-fragments (registers): q = q0 + w*32 + qs*16 + ln
    bf16x8 qf[2][2];
#pragma unroll
    for (int qs = 0; qs < 2; ++qs) {
        const ushort* qrow = Qb + ((size_t)(b*S_ + q0 + w*32 + qs*16 + ln))*H_ + h*HD_ + lq*8;
        qf[qs][0] = *reinterpret_cast<const bf16x8*>(qrow);
        qf[qs][1] = *reinterpret_cast<const bf16x8*>(qrow + 32);
    }

    // staging: thread covers chunks {t, 256+t}; swizzled source (T21)
    size_t koff[2], voff[2];
    int    dsto[2];
#pragma unroll
    for (int i = 0; i < 2; ++i) {
        const int chunk = i*256 + t;
        const int row   = chunk >> 3;
        const int c8    = (chunk & 7) ^ (row & 7);
        koff[i] = (size_t)(b*S_ + row)*H_ + h*HD_ + c8*8;
        voff[i] = ((size_t)((b*NH_ + h)*HD_ + row))*S_ + c8*8;
        dsto[i] = chunk*8;
    }

    float lsum[2] = {0.f, 0.f};
    f32x4 oacc[2][4];
#pragma unroll
    for (int qs = 0; qs < 2; ++qs)
#pragma unroll
        for (int nt = 0; nt < 4; ++nt) oacc[qs][nt] = f32x4{0.f, 0.f, 0.f, 0.f};

    for (int kt = 0; kt < S_; kt += 64) {
        __syncthreads();
#pragma unroll
        for (int i = 0; i < 2; ++i)
            gload_lds16(Kb + koff[i] + (size_t)kt*H_, &Ks[dsto[i]]);
#pragma unroll
        for (int i = 0; i < 2; ++i)
            gload_lds16(Vtg + voff[i] + kt, &Vs[dsto[i]]);
        __syncthreads();

        // swapped QK^T: sacc[qs][nt] = K_nt · Q_qs^T  (rows=keys, cols=q)
        f32x4 sacc[2][4];
#pragma unroll
        for (int qs = 0; qs < 2; ++qs)
#pragma unroll
            for (int nt = 0; nt < 4; ++nt) sacc[qs][nt] = f32x4{0.f, 0.f, 0.f, 0.f};
#pragma unroll
        for (int ks = 0; ks < 2; ++ks) {
            bf16x8 kb[4];
#pragma unroll
            for (int nt = 0; nt < 4; ++nt)
                kb[nt] = *reinterpret_cast<const bf16x8*>(
                    &Ks[(nt*16 + ln)*64 + (((ks*4 + lq) ^ (ln & 7)) * 8)]);
#pragma unroll
            for (int qs = 0; qs < 2; ++qs)
#pragma unroll
                for (int nt = 0; nt < 4; ++nt)
                    sacc[qs][nt] = __builtin_amdgcn_mfma_f32_16x16x32_bf16(
                        kb[nt], qf[qs][ks], sacc[qs][nt], 0, 0, 0);
        }

        // e = exp2(s*SC2); lane-local lsum; packed b64 P store
        // lane (lq,ln): q = qs*16+ln, keys = nt*16 + lq*4 + r
#pragma unroll
        for (int qs = 0; qs < 2; ++qs) {
#pragma unroll
            for (int nt = 0; nt < 4; ++nt) {
                ushort pk[4];
#pragma unroll
                for (int r = 0; r < 4; ++r) {
                    const float e = exp2f(sacc[qs][nt][r] * SC2);
                    lsum[qs] += e;
                    pk[r] = f2bf(e);
                }
                *reinterpret_cast<uint2*>(&Ps[w][qs*16 + ln][nt*16 + lq*4]) =
                    *reinterpret_cast<uint2*>(pk);
            }
        }

        // PV (Ps wave-private; in-order DS within wave)
#pragma unroll
        for (int ks = 0; ks < 2; ++ks) {
            bf16x8 pa[2];
#pragma unroll
            for (int qs = 0; qs < 2; ++qs)
                pa[qs] = *reinterpret_cast<const bf16x8*>(&Ps[w][qs*16 + ln][ks*32 + lq*8]);
#pragma unroll
            for (int nt = 0; nt < 4; ++nt) {
                const bf16x8 vb8 = *reinterpret_cast<const bf16x8*>(
                    &Vs[(nt*16 + ln)*64 + (((ks*4 + lq) ^ (ln & 7)) * 8)]);
#pragma unroll
                for (int qs = 0; qs < 2; ++qs)
                    oacc[qs][nt] = __builtin_amdgcn_mfma_f32_16x16x32_bf16(
                        pa[qs], vb8, oacc[qs][nt], 0, 0, 0);
            }
        }
    }

    // row sums: reduce across lq groups -> invl for q = qs*16 + ln
    float invl[2];
#pragma unroll
    for (int qs = 0; qs < 2; ++qs) {
        lsum[qs] += __shfl_xor(lsum[qs], 16);
        lsum[qs] += __shfl_xor(lsum[qs], 32);
        invl[qs] = 1.f / lsum[qs];
    }

    if (lq == 0) {
#pragma unroll
        for (int qs = 0; qs < 2; ++qs)
            invl_g[(size_t)(b*NH_ + h)*S_ + q0 + w*32 + qs*16 + ln] = invl[qs];
    }

    // ctx write: oacc D rows = q local lq*4+r -> need invl of那 row via shfl
#pragma unroll
    for (int qs = 0; qs < 2; ++qs) {
        float ivr[4];
#pragma unroll
        for (int r = 0; r < 4; ++r) ivr[r] = __shfl(invl[qs], lq*4 + r);
        ushort* crow = ctx + ((size_t)(b*S_ + q0 + w*32 + qs*16 + lq*4))*H_ + h*HD_ + ln;
#pragma unroll
        for (int r = 0; r < 4; ++r)
#pragma unroll
            for (int nt = 0; nt < 4; ++nt)
                crow[(size_t)r*H_ + nt*16] = f2bf(oacc[qs][nt][r] * ivr[r]);
    }
}

// ---------------------------------------------------------------
// attn_colsum (round 6): 128-key blocks. K B-frags in regs, invl in
// LDS; sweep q-tiles: QK + exp2*invl -> register colsum.
// Wave w owns keys [w*32, +32) as 2 sub-tiles of 16.
// ---------------------------------------------------------------
__global__ __launch_bounds__(256) void attn_colsum(
    const ushort* __restrict__ Qb, const ushort* __restrict__ Kb,
    const float* __restrict__ invl_g, float* __restrict__ colsum)
{
    __shared__ __align__(16) ushort KsT[128*64];  // swizzled K tile
    __shared__ __align__(16) ushort Qs[64*64];    // swizzled Q tile
    __shared__ __align__(16) float  iv[S_];       // invl row for (b,h)

    const int t  = threadIdx.x;
    const int w  = t >> 6;
    const int l  = t & 63;
    const int lq = l >> 4;
    const int ln = l & 15;
    const int b  = blockIdx.z;
    const int h  = blockIdx.y;
    const int k0 = blockIdx.x * 128;
    const int bh = b*NH_ + h;

    // stage K (1024 chunks) + iv (512 chunks)
#pragma unroll
    for (int i = 0; i < 4; ++i) {
        const int chunk = i*256 + t;
        const int row   = chunk >> 3;
        const int c8    = (chunk & 7) ^ (row & 7);
        gload_lds16(Kb + (size_t)(b*S_ + k0 + row)*H_ + h*HD_ + c8*8, &KsT[chunk*8]);
    }
#pragma unroll
    for (int i = 0; i < 2; ++i) {
        const int chunk = i*256 + t;
        gload_lds16(invl_g + (size_t)bh*S_ + chunk*4, &iv[chunk*4]);
    }

    // Q staging chunk math
    int qrow[2], qc8[2];
#pragma unroll
    for (int i = 0; i < 2; ++i) {
        const int chunk = i*256 + t;
        qrow[i] = chunk >> 3;
        qc8[i]  = (chunk & 7) ^ (qrow[i] & 7);
    }

    __syncthreads();

    // hoist this wave's K B-fragments (keys w*32 + sub*16 + ln)
    bf16x8 kf[2][2];
#pragma unroll
    for (int sub = 0; sub < 2; ++sub)
#pragma unroll
        for (int ks = 0; ks < 2; ++ks)
            kf[sub][ks] = *reinterpret_cast<const bf16x8*>(
                &KsT[(w*32 + sub*16 + ln)*64 + (((ks*4 + lq) ^ (ln & 7)) * 8)]);

    float cs[2] = {0.f, 0.f};

    for (int qt = 0; qt < S_; qt += 64) {
        __syncthreads();
#pragma unroll
        for (int i = 0; i < 2; ++i)
            gload_lds16(Qb + (size_t)(b*S_ + qt + qrow[i])*H_ + h*HD_ + qc8[i]*8,
                        &Qs[(i*256 + t)*8]);
        __syncthreads();

#pragma unroll
        for (int c = 0; c < 4; ++c) {
            f32x4 sacc[2] = {f32x4{0.f,0.f,0.f,0.f}, f32x4{0.f,0.f,0.f,0.f}};
#pragma unroll
            for (int ks = 0; ks < 2; ++ks) {
                const bf16x8 af = *reinterpret_cast<const bf16x8*>(
                    &Qs[(c*16 + ln)*64 + (((ks*4 + lq) ^ (ln & 7)) * 8)]);
#pragma unroll
                for (int sub = 0; sub < 2; ++sub)
                    sacc[sub] = __builtin_amdgcn_mfma_f32_16x16x32_bf16(
                        af, kf[sub][ks], sacc[sub], 0, 0, 0);
            }
            const f32x4 iv4 = *reinterpret_cast<const f32x4*>(&iv[qt + c*16 + lq*4]);
#pragma unroll
            for (int sub = 0; sub < 2; ++sub)
#pragma unroll
                for (int r = 0; r < 4; ++r)
                    cs[sub] += exp2f(sacc[sub][r] * SC2) * iv4[r];
        }
    }

#pragma unroll
    for (int sub = 0; sub < 2; ++sub) {
        cs[sub] += __shfl_xor(cs[sub], 16);
        cs[sub] += __shfl_xor(cs[sub], 32);
    }
    if (l < 16) {
#pragma unroll
        for (int sub = 0; sub < 2; ++sub)
            atomicAdd(&colsum[(size_t)b*S_ + k0 + w*32 + sub*16 + l], cs[sub]);
    }
}

__global__ void zero_f32(float* p, int n)
{
    const int i = blockIdx.x * 256 + threadIdx.x;
    if (i < n) p[i] = 0.f;
}

__global__ void avg_write(const float* __restrict__ colsum, float* __restrict__ out, float inv)
{
    const int i = blockIdx.x * 256 + threadIdx.x;
    if (i < NTOK) out[i] = colsum[i] * inv;
}

extern "C" void kernel_launch(void* const* d_in, const int* in_sizes, int n_in,
                              void* d_out, int out_size, void* d_ws, size_t ws_size,
                              hipStream_t stream)
{
    const float* x  = (const float*)d_in[0];
    const float* Wq = (const float*)d_in[1];
    const float* bq = (const float*)d_in[2];
    const float* Wk = (const float*)d_in[3];
    const float* bk = (const float*)d_in[4];
    const float* Wv = (const float*)d_in[5];
    const float* bv = (const float*)d_in[6];
    const float* Wo = (const float*)d_in[7];
    const float* bo = (const float*)d_in[8];

    float* out     = (float*)d_out;
    float* avg_out = out + (size_t)NTOK * H_;

    char* ws = (char*)d_ws;
    const size_t mat  = (size_t)NTOK * H_ * sizeof(ushort);   // 8 MB
    const size_t wmat = (size_t)H_ * H_ * sizeof(ushort);     // 2 MB
    ushort* xb   = (ushort*)(ws);                  // also ctx (x dead after projections)
    ushort* Qb   = (ushort*)(ws + mat);
    ushort* Kb   = (ushort*)(ws + 2*mat);
    ushort* Vb   = (ushort*)(ws + 3*mat);
    ushort* Vtg  = (ushort*)(ws + 4*mat);          // V^T [(b,h)][d][s]
    ushort* Wqb  = (ushort*)(ws + 5*mat);
    ushort* Wkb  = (ushort*)(ws + 5*mat + wmat);
    ushort* Wvb  = (ushort*)(ws + 5*mat + 2*wmat);
    ushort* Wob  = (ushort*)(ws + 5*mat + 3*wmat);
    float*  colsum = (float*)(ws + 5*mat + 4*wmat);                   // 16 KB
    float*  invl   = (float*)(ws + 5*mat + 4*wmat + 64*1024);         // 256 KB
    ushort* ctxb = xb;

    const dim3 blk(256);

    f32_to_bf16<<<dim3((NTOK*H_/8 + 255)/256), blk, 0, stream>>>(x, xb, NTOK*H_/8);
    {
        Cvt4 c;
        c.s[0] = Wq; c.s[1] = Wk; c.s[2] = Wv; c.s[3] = Wo;
        c.d[0] = Wqb; c.d[1] = Wkb; c.d[2] = Wvb; c.d[3] = Wob;
        w_to_bf16<<<dim3((H_*H_/8 + 255)/256, 4), blk, 0, stream>>>(c, H_*H_/8);
    }

    zero_f32<<<dim3((NTOK + 255)/256), blk, 0, stream>>>(colsum, NTOK);

    // fused QKV projections
    {
        GemmArgs ga;
        ga.W[0] = Wqb; ga.W[1] = Wkb; ga.W[2] = Wvb;
        ga.bias[0] = bq; ga.bias[1] = bk; ga.bias[2] = bv;
        ga.Y[0] = Qb; ga.Y[1] = Kb; ga.Y[2] = Vb;
        gemm_mfma_bt<4, true><<<dim3(NTOK/128, H_/128, 3), blk, 0, stream>>>(
            xb, ga, NTOK, H_, H_);
    }

    transpose_v<<<dim3(S_/64, NH_, B_), blk, 0, stream>>>(Vb, Vtg);

    attn_pv<<<dim3(S_/128, NH_, B_), blk, 0, stream>>>(Qb, Kb, Vtg, ctxb, invl);
    attn_colsum<<<dim3(S_/128, NH_, B_), blk, 0, stream>>>(Qb, Kb, invl, colsum);

    // out projection
    {
        GemmArgs ga;
        ga.W[0] = Wob; ga.W[1] = Wob; ga.W[2] = Wob;
        ga.bias[0] = bo; ga.bias[1] = bo; ga.bias[2] = bo;
        ga.Y[0] = out; ga.Y[1] = out; ga.Y[2] = out;
        gemm_mfma_bt<2, false><<<dim3(NTOK/64, H_/128, 1), blk, 0, stream>>>(
            ctxb, ga, NTOK, H_, H_);
    }

    avg_write<<<dim3((NTOK + 255)/256), blk, 0, stream>>>(colsum, avg_out, 1.f/((float)NH_ * (float)S_));
}

// Round 7
// 210.942 us; speedup vs baseline: 1.0503x; 1.0503x over previous
//
#include <hip/hip_runtime.h>
#include <hip/hip_bf16.h>

#define B_  2
#define S_  2048
#define H_  1024
#define NH_ 16
#define HD_ 64
#define NTOK (B_*S_)   // 4096

typedef __attribute__((ext_vector_type(8))) short bf16x8;
typedef __attribute__((ext_vector_type(4))) float f32x4;

#define SC2 0.18033688011112042f   // (1/sqrt(64)) * log2(e)

static __device__ __forceinline__ ushort f2bf(float f) {
    __hip_bfloat16 h = __float2bfloat16(f);
    return *reinterpret_cast<ushort*>(&h);
}
static __device__ __forceinline__ uint f2bf2(float lo, float hi) {
    __hip_bfloat162 v = __float22bfloat162_rn(float2{lo, hi});
    return *reinterpret_cast<uint*>(&v);
}

static __device__ __forceinline__ void gload_lds16(const void* g, void* l) {
    __builtin_amdgcn_global_load_lds(
        (const __attribute__((address_space(1))) void*)g,
        (__attribute__((address_space(3))) void*)l,
        16, 0, 0);
}

// ---------------------------------------------------------------
// f32 -> bf16 bulk converts
// ---------------------------------------------------------------
__global__ __launch_bounds__(256) void f32_to_bf16(
    const float* __restrict__ s, ushort* __restrict__ d, int n8)
{
    const int i = blockIdx.x * 256 + threadIdx.x;
    if (i >= n8) return;
    const float4 a = reinterpret_cast<const float4*>(s)[2*i + 0];
    const float4 b = reinterpret_cast<const float4*>(s)[2*i + 1];
    ushort u[8];
    u[0] = f2bf(a.x); u[1] = f2bf(a.y); u[2] = f2bf(a.z); u[3] = f2bf(a.w);
    u[4] = f2bf(b.x); u[5] = f2bf(b.y); u[6] = f2bf(b.z); u[7] = f2bf(b.w);
    reinterpret_cast<uint4*>(d)[i] = *reinterpret_cast<uint4*>(u);
}

struct Cvt4 { const float* s[4]; ushort* d[4]; };
__global__ __launch_bounds__(256) void w_to_bf16(Cvt4 a, int n8)
{
    const int z = blockIdx.y;
    const int i = blockIdx.x * 256 + threadIdx.x;
    if (i >= n8) return;
    const float* s = a.s[z];
    const float4 va = reinterpret_cast<const float4*>(s)[2*i + 0];
    const float4 vb = reinterpret_cast<const float4*>(s)[2*i + 1];
    ushort u[8];
    u[0] = f2bf(va.x); u[1] = f2bf(va.y); u[2] = f2bf(va.z); u[3] = f2bf(va.w);
    u[4] = f2bf(vb.x); u[5] = f2bf(vb.y); u[6] = f2bf(vb.z); u[7] = f2bf(vb.w);
    reinterpret_cast<uint4*>(a.d[z])[i] = *reinterpret_cast<uint4*>(u);
}

// ---------------------------------------------------------------
// V [tok][H] bf16 -> Vt [(b*NH+h)][d][s] bf16
// ---------------------------------------------------------------
__global__ __launch_bounds__(256) void transpose_v(
    const ushort* __restrict__ Vb, ushort* __restrict__ Vt)
{
    __shared__ ushort T[64][72];
    const int t  = threadIdx.x;
    const int b  = blockIdx.z;
    const int h  = blockIdx.y;
    const int s0 = blockIdx.x * 64;
    const int r  = t >> 2;
    const int c0 = (t & 3) * 16;

    const ushort* src = Vb + (size_t)(b*S_ + s0 + r)*H_ + h*HD_ + c0;
    *reinterpret_cast<uint4*>(&T[r][c0])     = *reinterpret_cast<const uint4*>(src);
    *reinterpret_cast<uint4*>(&T[r][c0 + 8]) = *reinterpret_cast<const uint4*>(src + 8);
    __syncthreads();

    const int d = r;
    ushort tmp[16];
#pragma unroll
    for (int k = 0; k < 16; ++k) tmp[k] = T[c0 + k][d];
    ushort* dst = Vt + ((size_t)((b*NH_ + h)*HD_ + d))*S_ + s0 + c0;
    *reinterpret_cast<uint4*>(dst)     = *reinterpret_cast<uint4*>(&tmp[0]);
    *reinterpret_cast<uint4*>(dst + 8) = *reinterpret_cast<uint4*>(&tmp[8]);
}

// ---------------------------------------------------------------
// MFMA GEMM: Y = A(bf16,[M,K]) @ W(bf16,[N,K])^T + bias(f32)
// ---------------------------------------------------------------
struct GemmArgs {
    const ushort* W[3];
    const float*  bias[3];
    void*         Y[3];
};

template<int MREP, bool BF16OUT>
__global__ __launch_bounds__(256) void gemm_mfma_bt(
    const ushort* __restrict__ A, GemmArgs args, int M, int N, int K)
{
    constexpr int BM = MREP * 32;
    __shared__ __align__(16) ushort As[BM * 64];
    __shared__ __align__(16) ushort Bs[128 * 64];

    const int z = blockIdx.z;
    const ushort* __restrict__ W   = args.W[z];
    const float*  __restrict__ bia = args.bias[z];

    const int t  = threadIdx.x;
    const int w  = t >> 6;
    const int l  = t & 63;
    const int lq = l >> 4;
    const int ln = l & 15;
    const int wr = w >> 1;
    const int wc = w & 1;
    const int m0 = blockIdx.x * BM;
    const int n0 = blockIdx.y * 128;
    const int srow = l >> 3;
    const int scol = (l & 7) * 8;

    f32x4 acc[MREP][4];
#pragma unroll
    for (int m = 0; m < MREP; ++m)
#pragma unroll
        for (int n = 0; n < 4; ++n) acc[m][n] = f32x4{0.f, 0.f, 0.f, 0.f};

    for (int k0 = 0; k0 < K; k0 += 64) {
        __syncthreads();
#pragma unroll
        for (int i = 0; i < BM/32; ++i) {
            const int rb = i*32 + w*8;
            gload_lds16(A + (size_t)(m0 + rb + srow)*K + k0 + scol, &As[rb*64]);
        }
#pragma unroll
        for (int i = 0; i < 4; ++i) {
            const int rb = i*32 + w*8;
            gload_lds16(W + (size_t)(n0 + rb + srow)*K + k0 + scol, &Bs[rb*64]);
        }
        __syncthreads();
#pragma unroll
        for (int ks = 0; ks < 2; ++ks) {
            bf16x8 bfr[4];
#pragma unroll
            for (int n = 0; n < 4; ++n)
                bfr[n] = *reinterpret_cast<const bf16x8*>(&Bs[(wc*64 + n*16 + ln)*64 + ks*32 + lq*8]);
#pragma unroll
            for (int m = 0; m < MREP; ++m) {
                const bf16x8 afr = *reinterpret_cast<const bf16x8*>(&As[(wr*MREP*16 + m*16 + ln)*64 + ks*32 + lq*8]);
#pragma unroll
                for (int n = 0; n < 4; ++n)
                    acc[m][n] = __builtin_amdgcn_mfma_f32_16x16x32_bf16(afr, bfr[n], acc[m][n], 0, 0, 0);
            }
        }
    }

    float bv[4];
#pragma unroll
    for (int n = 0; n < 4; ++n) bv[n] = bia[n0 + wc*64 + n*16 + ln];

#pragma unroll
    for (int m = 0; m < MREP; ++m) {
#pragma unroll
        for (int r = 0; r < 4; ++r) {
            const size_t row = (size_t)(m0 + wr*MREP*16 + m*16 + lq*4 + r);
#pragma unroll
            for (int n = 0; n < 4; ++n) {
                const int col = n0 + wc*64 + n*16 + ln;
                const float val = acc[m][n][r] + bv[n];
                if constexpr (BF16OUT)
                    ((ushort*)args.Y[z])[row*N + col] = f2bf(val);
                else
                    ((float*)args.Y[z])[row*N + col] = val;
            }
        }
    }
}

// ---------------------------------------------------------------
// attn_pv (round 7): QB=64, swapped QK^T, deferred normalization,
// 2-phase pipeline: K double-buffered (prefetch t+1 under compute t),
// V single-buffered with counted vmcnt(2) + raw s_barrier mid-iter.
// Writes ctx (bf16, normalized) and il2 = -log2(lsum).
// ---------------------------------------------------------------
__global__ __launch_bounds__(256) void attn_pv(
    const ushort* __restrict__ Qb, const ushort* __restrict__ Kb,
    const ushort* __restrict__ Vtg, ushort* __restrict__ ctx,
    float* __restrict__ il2_g)
{
    __shared__ __align__(16) ushort Ks[2][64*64];   // swizzled K tiles (dbuf)
    __shared__ __align__(16) ushort Vs[64*64];      // swizzled V^T tile
    __shared__ __align__(16) ushort Ps[4][16][72];  // per-wave P [qrow][key]

    const int t  = threadIdx.x;
    const int w  = t >> 6;
    const int l  = t & 63;
    const int lq = l >> 4;
    const int ln = l & 15;
    const int b  = blockIdx.z;
    const int h  = blockIdx.y;
    const int q0 = blockIdx.x * 64;

    // Q B-fragments (registers): q = q0 + w*16 + ln
    bf16x8 qf[2];
    {
        const ushort* qrow = Qb + ((size_t)(b*S_ + q0 + w*16 + ln))*H_ + h*HD_ + lq*8;
        qf[0] = *reinterpret_cast<const bf16x8*>(qrow);
        qf[1] = *reinterpret_cast<const bf16x8*>(qrow + 32);
    }

    // staging: thread covers chunks {t, 256+t}; swizzled source (T21)
    size_t koff[2], voff[2];
    int    dsto[2];
#pragma unroll
    for (int i = 0; i < 2; ++i) {
        const int chunk = i*256 + t;
        const int row   = chunk >> 3;
        const int c8    = (chunk & 7) ^ (row & 7);
        koff[i] = (size_t)(b*S_ + row)*H_ + h*HD_ + c8*8;
        voff[i] = ((size_t)((b*NH_ + h)*HD_ + row))*S_ + c8*8;
        dsto[i] = chunk*8;
    }

    float lsum = 0.f;
    f32x4 oacc[4];
#pragma unroll
    for (int nt = 0; nt < 4; ++nt) oacc[nt] = f32x4{0.f, 0.f, 0.f, 0.f};

    // prologue: stage K(0) into buf 0
#pragma unroll
    for (int i = 0; i < 2; ++i)
        gload_lds16(Kb + koff[i], &Ks[0][dsto[i]]);
    __syncthreads();

    int cur = 0;
    for (int kt = 0; kt < S_; kt += 64) {
        // issue V(t) FIRST, then K(t+1) prefetch
#pragma unroll
        for (int i = 0; i < 2; ++i)
            gload_lds16(Vtg + voff[i] + kt, &Vs[dsto[i]]);
        const bool pre = (kt + 64 < S_);
        if (pre) {
#pragma unroll
            for (int i = 0; i < 2; ++i)
                gload_lds16(Kb + koff[i] + (size_t)(kt + 64)*H_, &Ks[cur ^ 1][dsto[i]]);
        }

        // swapped QK^T from Ks[cur] (landed via previous barrier drain)
        const ushort* ksb = &Ks[cur][0];
        f32x4 sacc[4];
#pragma unroll
        for (int nt = 0; nt < 4; ++nt) sacc[nt] = f32x4{0.f, 0.f, 0.f, 0.f};
#pragma unroll
        for (int ks = 0; ks < 2; ++ks) {
            bf16x8 kb[4];
#pragma unroll
            for (int nt = 0; nt < 4; ++nt)
                kb[nt] = *reinterpret_cast<const bf16x8*>(
                    &ksb[(nt*16 + ln)*64 + (((ks*4 + lq) ^ (ln & 7)) * 8)]);
#pragma unroll
            for (int nt = 0; nt < 4; ++nt)
                sacc[nt] = __builtin_amdgcn_mfma_f32_16x16x32_bf16(
                    kb[nt], qf[ks], sacc[nt], 0, 0, 0);
        }

        // e = exp2(s*SC2); lane-local lsum; packed b64 P store
        // lane (lq,ln): q = ln, keys = nt*16 + lq*4 + r
#pragma unroll
        for (int nt = 0; nt < 4; ++nt) {
            float e[4];
#pragma unroll
            for (int r = 0; r < 4; ++r) {
                e[r] = exp2f(sacc[nt][r] * SC2);
                lsum += e[r];
            }
            uint2 pk;
            pk.x = f2bf2(e[0], e[1]);
            pk.y = f2bf2(e[2], e[3]);
            *reinterpret_cast<uint2*>(&Ps[w][ln][nt*16 + lq*4]) = pk;
        }

        // V(t) landed? counted wait: K-prefetch (2 newest) may stay in flight
        if (pre) asm volatile("s_waitcnt vmcnt(2)" ::: "memory");
        else     asm volatile("s_waitcnt vmcnt(0)" ::: "memory");
        __builtin_amdgcn_s_barrier();
        __builtin_amdgcn_sched_barrier(0);

        // PV from Vs + Ps (Ps wave-private, in-order within wave)
#pragma unroll
        for (int ks = 0; ks < 2; ++ks) {
            const bf16x8 pa = *reinterpret_cast<const bf16x8*>(&Ps[w][ln][ks*32 + lq*8]);
#pragma unroll
            for (int nt = 0; nt < 4; ++nt) {
                const bf16x8 vb8 = *reinterpret_cast<const bf16x8*>(
                    &Vs[(nt*16 + ln)*64 + (((ks*4 + lq) ^ (ln & 7)) * 8)]);
                oacc[nt] = __builtin_amdgcn_mfma_f32_16x16x32_bf16(
                    pa, vb8, oacc[nt], 0, 0, 0);
            }
        }

        __syncthreads();   // full drain: K(t+1) landed, all waves done with Vs/Ks[cur]
        cur ^= 1;
    }

    // reduce lsum across lq groups -> denominator for q = ln
    lsum += __shfl_xor(lsum, 16);
    lsum += __shfl_xor(lsum, 32);
    const float invl = 1.f / lsum;

    if (lq == 0)
        il2_g[(size_t)(b*NH_ + h)*S_ + q0 + w*16 + ln] = -__log2f(lsum);

    // ctx write: oacc rows = q local lq*4+r -> invl of that row via shfl
    float ivr[4];
#pragma unroll
    for (int r = 0; r < 4; ++r) ivr[r] = __shfl(invl, lq*4 + r);
    ushort* crow = ctx + ((size_t)(b*S_ + q0 + w*16 + lq*4))*H_ + h*HD_ + ln;
#pragma unroll
    for (int r = 0; r < 4; ++r)
#pragma unroll
        for (int nt = 0; nt < 4; ++nt)
            crow[(size_t)r*H_ + nt*16] = f2bf(oacc[nt][r] * ivr[r]);
}

// ---------------------------------------------------------------
// attn_colsum (round 7): 64-key blocks, Q double-buffered prefetch,
// exponent-folded normalization: cs += exp2(fma(s, SC2, il2[q])).
// Wave w owns keys [w*16, +16).
// ---------------------------------------------------------------
__global__ __launch_bounds__(256) void attn_colsum(
    const ushort* __restrict__ Qb, const ushort* __restrict__ Kb,
    const float* __restrict__ il2_g, float* __restrict__ colsum)
{
    __shared__ __align__(16) ushort KsT[64*64];    // swizzled K tile
    __shared__ __align__(16) ushort Qs[2][64*64];  // swizzled Q tiles (dbuf)
    __shared__ __align__(16) float  iv[S_];        // il2 row for (b,h)

    const int t  = threadIdx.x;
    const int w  = t >> 6;
    const int l  = t & 63;
    const int lq = l >> 4;
    const int ln = l & 15;
    const int b  = blockIdx.z;
    const int h  = blockIdx.y;
    const int k0 = blockIdx.x * 64;
    const int bh = b*NH_ + h;

    // staging chunk math
    int crow_[2], cc8[2], dsto[2];
#pragma unroll
    for (int i = 0; i < 2; ++i) {
        const int chunk = i*256 + t;
        crow_[i] = chunk >> 3;
        cc8[i]   = (chunk & 7) ^ (crow_[i] & 7);
        dsto[i]  = chunk*8;
    }

    // prologue: K tile + il2 row + Q(0)
#pragma unroll
    for (int i = 0; i < 2; ++i) {
        gload_lds16(Kb + (size_t)(b*S_ + k0 + crow_[i])*H_ + h*HD_ + cc8[i]*8, &KsT[dsto[i]]);
        gload_lds16(il2_g + (size_t)bh*S_ + (i*256 + t)*4, &iv[(i*256 + t)*4]);
        gload_lds16(Qb + (size_t)(b*S_ + crow_[i])*H_ + h*HD_ + cc8[i]*8, &Qs[0][dsto[i]]);
    }
    __syncthreads();

    // hoist this wave's K B-fragments (keys w*16 + ln)
    bf16x8 kf[2];
#pragma unroll
    for (int ks = 0; ks < 2; ++ks)
        kf[ks] = *reinterpret_cast<const bf16x8*>(
            &KsT[(w*16 + ln)*64 + (((ks*4 + lq) ^ (ln & 7)) * 8)]);

    float cs = 0.f;   // colsum for key k0 + w*16 + ln (partial over lq)

    int cur = 0;
    for (int qt = 0; qt < S_; qt += 64) {
        if (qt + 64 < S_) {
#pragma unroll
            for (int i = 0; i < 2; ++i)
                gload_lds16(Qb + (size_t)(b*S_ + qt + 64 + crow_[i])*H_ + h*HD_ + cc8[i]*8,
                            &Qs[cur ^ 1][dsto[i]]);
        }
        const ushort* qsb = &Qs[cur][0];

#pragma unroll
        for (int c = 0; c < 4; ++c) {
            f32x4 sacc = f32x4{0.f, 0.f, 0.f, 0.f};
#pragma unroll
            for (int ks = 0; ks < 2; ++ks) {
                const bf16x8 af = *reinterpret_cast<const bf16x8*>(
                    &qsb[(c*16 + ln)*64 + (((ks*4 + lq) ^ (ln & 7)) * 8)]);
                sacc = __builtin_amdgcn_mfma_f32_16x16x32_bf16(af, kf[ks], sacc, 0, 0, 0);
            }
            const f32x4 iv4 = *reinterpret_cast<const f32x4*>(&iv[qt + c*16 + lq*4]);
#pragma unroll
            for (int r = 0; r < 4; ++r)
                cs += exp2f(fmaf(sacc[r], SC2, iv4[r]));
        }

        __syncthreads();   // Q(t+1) landed; all waves done with Qs[cur]
        cur ^= 1;
    }

    cs += __shfl_xor(cs, 16);
    cs += __shfl_xor(cs, 32);
    if (l < 16)
        atomicAdd(&colsum[(size_t)b*S_ + k0 + w*16 + l], cs);
}

__global__ void zero_f32(float* p, int n)
{
    const int i = blockIdx.x * 256 + threadIdx.x;
    if (i < n) p[i] = 0.f;
}

__global__ void avg_write(const float* __restrict__ colsum, float* __restrict__ out, float inv)
{
    const int i = blockIdx.x * 256 + threadIdx.x;
    if (i < NTOK) out[i] = colsum[i] * inv;
}

extern "C" void kernel_launch(void* const* d_in, const int* in_sizes, int n_in,
                              void* d_out, int out_size, void* d_ws, size_t ws_size,
                              hipStream_t stream)
{
    const float* x  = (const float*)d_in[0];
    const float* Wq = (const float*)d_in[1];
    const float* bq = (const float*)d_in[2];
    const float* Wk = (const float*)d_in[3];
    const float* bk = (const float*)d_in[4];
    const float* Wv = (const float*)d_in[5];
    const float* bv = (const float*)d_in[6];
    const float* Wo = (const float*)d_in[7];
    const float* bo = (const float*)d_in[8];

    float* out     = (float*)d_out;
    float* avg_out = out + (size_t)NTOK * H_;

    char* ws = (char*)d_ws;
    const size_t mat  = (size_t)NTOK * H_ * sizeof(ushort);   // 8 MB
    const size_t wmat = (size_t)H_ * H_ * sizeof(ushort);     // 2 MB
    ushort* xb   = (ushort*)(ws);                  // also ctx (x dead after projections)
    ushort* Qb   = (ushort*)(ws + mat);
    ushort* Kb   = (ushort*)(ws + 2*mat);
    ushort* Vb   = (ushort*)(ws + 3*mat);
    ushort* Vtg  = (ushort*)(ws + 4*mat);          // V^T [(b,h)][d][s]
    ushort* Wqb  = (ushort*)(ws + 5*mat);
    ushort* Wkb  = (ushort*)(ws + 5*mat + wmat);
    ushort* Wvb  = (ushort*)(ws + 5*mat + 2*wmat);
    ushort* Wob  = (ushort*)(ws + 5*mat + 3*wmat);
    float*  colsum = (float*)(ws + 5*mat + 4*wmat);                   // 16 KB
    float*  il2    = (float*)(ws + 5*mat + 4*wmat + 64*1024);         // 256 KB
    ushort* ctxb = xb;

    const dim3 blk(256);

    f32_to_bf16<<<dim3((NTOK*H_/8 + 255)/256), blk, 0, stream>>>(x, xb, NTOK*H_/8);
    {
        Cvt4 c;
        c.s[0] = Wq; c.s[1] = Wk; c.s[2] = Wv; c.s[3] = Wo;
        c.d[0] = Wqb; c.d[1] = Wkb; c.d[2] = Wvb; c.d[3] = Wob;
        w_to_bf16<<<dim3((H_*H_/8 + 255)/256, 4), blk, 0, stream>>>(c, H_*H_/8);
    }

    zero_f32<<<dim3((NTOK + 255)/256), blk, 0, stream>>>(colsum, NTOK);

    // fused QKV projections
    {
        GemmArgs ga;
        ga.W[0] = Wqb; ga.W[1] = Wkb; ga.W[2] = Wvb;
        ga.bias[0] = bq; ga.bias[1] = bk; ga.bias[2] = bv;
        ga.Y[0] = Qb; ga.Y[1] = Kb; ga.Y[2] = Vb;
        gemm_mfma_bt<4, true><<<dim3(NTOK/128, H_/128, 3), blk, 0, stream>>>(
            xb, ga, NTOK, H_, H_);
    }

    transpose_v<<<dim3(S_/64, NH_, B_), blk, 0, stream>>>(Vb, Vtg);

    attn_pv<<<dim3(S_/64, NH_, B_), blk, 0, stream>>>(Qb, Kb, Vtg, ctxb, il2);
    attn_colsum<<<dim3(S_/64, NH_, B_), blk, 0, stream>>>(Qb, Kb, il2, colsum);

    // out projection
    {
        GemmArgs ga;
        ga.W[0] = Wob; ga.W[1] = Wob; ga.W[2] = Wob;
        ga.bias[0] = bo; ga.bias[1] = bo; ga.bias[2] = bo;
        ga.Y[0] = out; ga.Y[1] = out; ga.Y[2] = out;
        gemm_mfma_bt<2, false><<<dim3(NTOK/64, H_/128, 1), blk, 0, stream>>>(
            ctxb, ga, NTOK, H_, H_);
    }

    avg_write<<<dim3((NTOK + 255)/256), blk, 0, stream>>>(colsum, avg_out, 1.f/((float)NH_ * (float)S_));
}